// Round 3
// baseline (1075.848 us; speedup 1.0000x reference)
//
#include <hip/hip_runtime.h>
#include <math.h>

#define H 300
#define BB 64
#define TT 512
#define VV 50257
#define KC 30

// ---------- transpose 300x300: out[r][c] = in[c][r] (U only; W read direct) ----------
__global__ void transpose_k(const float* __restrict__ in, float* __restrict__ out) {
    int idx = blockIdx.x * blockDim.x + threadIdx.x;
    if (idx < H * H) {
        int r = idx / H, c = idx - r * H;
        out[idx] = in[c * H + r];
    }
}

// ---------- ux[t][b][g] = sum_h emb[tok[b][t]][h] * U[g][h] ----------
__global__ __launch_bounds__(256) void ux_k(const int* __restrict__ tokens,
                                            const float* __restrict__ emb,
                                            const float* __restrict__ Ut,   // Ut[h][g] = U[g][h]
                                            float* __restrict__ ux) {
    __shared__ __align__(16) float x_s[KC][BB];
    __shared__ __align__(16) float ut_s[KC][304];
    __shared__ int tok_s[BB];

    const int t = blockIdx.x;
    const int tid = threadIdx.x;
    if (tid < BB) tok_s[tid] = tokens[tid * TT + t];

    const int tb = tid >> 4;
    const int tg = tid & 15;
    const int b0 = tb * 4;
    const int g0 = tg * 20;
    const bool active = (tg < 15);

    float acc[4][20];
#pragma unroll
    for (int i = 0; i < 4; ++i)
#pragma unroll
        for (int j = 0; j < 20; ++j) acc[i][j] = 0.f;

    __syncthreads();

    for (int h0 = 0; h0 < H; h0 += KC) {
        for (int i = tid; i < BB * 32; i += 256) {
            int b = i >> 5, k = i & 31;
            if (k < KC) x_s[k][b] = emb[tok_s[b] * H + h0 + k];
        }
        for (int i = tid; i < KC * H; i += 256) {
            int k = i / H, g = i - k * H;
            ut_s[k][g] = Ut[(h0 + k) * H + g];
        }
        __syncthreads();
        if (active) {
#pragma unroll 2
            for (int k = 0; k < KC; ++k) {
                float4 xa = *reinterpret_cast<const float4*>(&x_s[k][b0]);
                float4 u0 = *reinterpret_cast<const float4*>(&ut_s[k][g0 + 0]);
                float4 u1 = *reinterpret_cast<const float4*>(&ut_s[k][g0 + 4]);
                float4 u2 = *reinterpret_cast<const float4*>(&ut_s[k][g0 + 8]);
                float4 u3 = *reinterpret_cast<const float4*>(&ut_s[k][g0 + 12]);
                float4 u4 = *reinterpret_cast<const float4*>(&ut_s[k][g0 + 16]);
                const float xr[4] = {xa.x, xa.y, xa.z, xa.w};
                const float ur[20] = {u0.x, u0.y, u0.z, u0.w,
                                      u1.x, u1.y, u1.z, u1.w,
                                      u2.x, u2.y, u2.z, u2.w,
                                      u3.x, u3.y, u3.z, u3.w,
                                      u4.x, u4.y, u4.z, u4.w};
#pragma unroll
                for (int i = 0; i < 4; ++i)
#pragma unroll
                    for (int j = 0; j < 20; ++j)
                        acc[i][j] += xr[i] * ur[j];
            }
        }
        __syncthreads();
    }

    if (active) {
#pragma unroll
        for (int i = 0; i < 4; ++i) {
            float* dst = ux + (t * BB + b0 + i) * H + g0;
#pragma unroll
            for (int jq = 0; jq < 5; ++jq) {
                *reinterpret_cast<float4*>(dst + jq * 4) =
                    make_float4(acc[i][jq * 4 + 0], acc[i][jq * 4 + 1],
                                acc[i][jq * 4 + 2], acc[i][jq * 4 + 3]);
            }
        }
    }
}

// ---------- recurrence: one block per batch element ----------
// 960 threads (15 waves): jc = min(tid/300,2) owns h-chunk [jc*100, jc*100+100).
// W held in 25 NAMED float4s (no array -> nothing for SROA to miss).
// amdgpu_waves_per_eu(4,4): VGPR budget 512/4 = 128 (launch_bounds 2nd arg was
// misinterpreted in r2 -> regression; explicit attribute is unambiguous).
#define W_FOREACH(X) X(0) X(1) X(2) X(3) X(4) X(5) X(6) X(7) X(8) X(9) \
    X(10) X(11) X(12) X(13) X(14) X(15) X(16) X(17) X(18) X(19) \
    X(20) X(21) X(22) X(23) X(24)

__global__ __attribute__((amdgpu_flat_work_group_size(960, 960), amdgpu_waves_per_eu(4, 4)))
void rnn_k(const float* __restrict__ W,     // W[g][h], read directly (row-contiguous)
           const float* __restrict__ ux,    // [T][B][H]
           const float* __restrict__ ihs,
           float* __restrict__ hlast) {
    __shared__ __align__(16) float h_s[304];
    __shared__ float p_s[2 * 304];
    const int b = blockIdx.x;
    const int tid = threadIdx.x;
    const int g = tid % H;
    const int j = tid / H;
    const int jc = (j < 2) ? j : 2;          // tid 900..959 duplicate jc=2, g<60 (benign)

    // W[g][jc*100 + 4q .. +3]  -- contiguous, 16B-aligned (g*300+jc*100+4q all mult of 4)
    const float4* wrow = reinterpret_cast<const float4*>(W + (size_t)g * H + jc * 100);
#define W_DECL(q) float4 w##q = wrow[q];
    W_FOREACH(W_DECL)
#undef W_DECL

    if (tid < H) h_s[tid] = ihs[b * H + tid];
    __syncthreads();

    const float4* hs4 = reinterpret_cast<const float4*>(h_s);
    const int hs_off = jc * 25;
    const float* uxb = ux + b * H;

#pragma unroll 1
    for (int t = 0; t < TT; ++t) {
        float uv = 0.f;
        if (tid < H) uv = uxb[t * (BB * H) + g];   // independent of h_s; issues early
        float acc0 = 0.f, acc1 = 0.f, acc2 = 0.f, acc3 = 0.f;
#define W_STEP(q) { float4 h4 = hs4[hs_off + q]; \
        acc0 += w##q.x * h4.x; acc1 += w##q.y * h4.y; \
        acc2 += w##q.z * h4.z; acc3 += w##q.w * h4.w; }
        W_FOREACH(W_STEP)
#undef W_STEP
        float acc = (acc0 + acc1) + (acc2 + acc3);
        if (j == 1) p_s[g] = acc;
        if (tid >= 2 * H) p_s[304 + g] = acc;
        __syncthreads();
        if (tid < H) {
            float z = acc + p_s[g] + p_s[304 + g] + uv;
            // tanh(z) = 1 - 2/(exp(2z)+1); exp inf/0 limits give +/-1 correctly
            float e = __expf(2.f * z);
            h_s[g] = 1.f - 2.f * __builtin_amdgcn_rcpf(e + 1.f);
        }
        __syncthreads();
    }
    if (tid < H) hlast[b * H + tid] = h_s[tid];
}

// ---------- logits: out[b][v] = h_last[b] . Wout[v] + bout[v] ----------
// 256 threads / 4 waves; wave handles 16 v-rows; block covers 64 rows.
// hlast staged TRANSPOSED hT[h][b] (+65 pad): 1 ds_read_b32 per h feeds 16 FMAs.
// Wout rows are wave-uniform -> s_load_dwordx4. Coalesced store via LDS transpose.
__global__ __launch_bounds__(256) void logits_k(const float* __restrict__ hlast,
                                                const float* __restrict__ Wout,
                                                const float* __restrict__ bout,
                                                float* __restrict__ out) {
    __shared__ float hT[152 * 65];             // 39.5 KB; reused for store epilogue
    const int tid = threadIdx.x;
    const int lane = tid & 63;                 // = b
    const int wv = tid >> 6;                   // 0..3
    const int v0 = blockIdx.x * 64;
    const int vbase = v0 + wv * 16;

    const float* wp[16];
#pragma unroll
    for (int r = 0; r < 16; ++r) {
        int vr = vbase + r; if (vr > VV - 1) vr = VV - 1;
        wp[r] = Wout + (size_t)vr * H;
    }

    float acc[16];
#pragma unroll
    for (int r = 0; r < 16; ++r) acc[r] = 0.f;

    for (int p = 0; p < 2; ++p) {
        const int hbase = p ? 148 : 0;         // 148/152 split keeps 16B alignment
        const int hn = p ? 152 : 148;
        __syncthreads();
        for (int i = tid; i < BB * hn; i += 256) {
            int b = i / hn, h = i - b * hn;    // lane-consecutive h: coalesced global
            hT[h * 65 + b] = hlast[b * H + hbase + h];  // stride-65 write: conflict-free
        }
        __syncthreads();
        for (int hc = 0; hc < hn; hc += 4) {
            float hv0 = hT[(hc + 0) * 65 + lane];
            float hv1 = hT[(hc + 1) * 65 + lane];
            float hv2 = hT[(hc + 2) * 65 + lane];
            float hv3 = hT[(hc + 3) * 65 + lane];
#pragma unroll
            for (int r = 0; r < 16; ++r) {
                const float4 w4 = *reinterpret_cast<const float4*>(wp[r] + hbase + hc);
                acc[r] += hv0 * w4.x + hv1 * w4.y + hv2 * w4.z + hv3 * w4.w;
            }
        }
    }

    // epilogue: transpose via LDS for coalesced stores
    __syncthreads();
#pragma unroll
    for (int r = 0; r < 16; ++r) hT[(wv * 16 + r) * 65 + lane] = acc[r];
    __syncthreads();
#pragma unroll
    for (int k = 0; k < 16; ++k) {
        int i = tid + k * 256;
        int v = i & 63, bb = i >> 6;
        if (v0 + v < VV)
            out[(size_t)bb * VV + v0 + v] = hT[v * 65 + bb] + bout[v0 + v];
    }
}

extern "C" void kernel_launch(void* const* d_in, const int* in_sizes, int n_in,
                              void* d_out, int out_size, void* d_ws, size_t ws_size,
                              hipStream_t stream) {
    const float* ihs    = (const float*)d_in[0];
    const int*   tokens = (const int*)  d_in[1];
    const float* emb    = (const float*)d_in[2];
    const float* W      = (const float*)d_in[3];
    const float* U      = (const float*)d_in[4];
    const float* Wout   = (const float*)d_in[5];
    const float* bout   = (const float*)d_in[6];
    float* out = (float*)d_out;

    char* ws = (char*)d_ws;
    float* Ut    = (float*)(ws + 0);          // 360,000 B
    float* hlast = (float*)(ws + 400000);     // 76,800 B
    float* ux    = (float*)(ws + 1048576);    // 39,321,600 B  [T][B][H]

    const int tp_blocks = (H * H + 255) / 256;
    transpose_k<<<tp_blocks, 256, 0, stream>>>(U, Ut);
    ux_k<<<TT, 256, 0, stream>>>(tokens, emb, Ut, ux);
    rnn_k<<<BB, 960, 0, stream>>>(W, ux, ihs, hlast);
    logits_k<<<(VV + 63) / 64, 256, 0, stream>>>(hlast, Wout, bout, out);
}

// Round 4
// 855.653 us; speedup vs baseline: 1.2573x; 1.2573x over previous
//
#include <hip/hip_runtime.h>
#include <math.h>

#define H 300
#define BB 64
#define TT 512
#define VV 50257
#define KC 30

// ---------- transpose 300x300: out[r][c] = in[c][r] (U only) ----------
__global__ void transpose_k(const float* __restrict__ in, float* __restrict__ out) {
    int idx = blockIdx.x * blockDim.x + threadIdx.x;
    if (idx < H * H) {
        int r = idx / H, c = idx - r * H;
        out[idx] = in[c * H + r];
    }
}

// ---------- ux[t][b][g] = sum_h emb[tok[b][t]][h] * U[g][h] ----------
__global__ __launch_bounds__(256) void ux_k(const int* __restrict__ tokens,
                                            const float* __restrict__ emb,
                                            const float* __restrict__ Ut,   // Ut[h][g] = U[g][h]
                                            float* __restrict__ ux) {
    __shared__ __align__(16) float x_s[KC][BB];
    __shared__ __align__(16) float ut_s[KC][304];
    __shared__ int tok_s[BB];

    const int t = blockIdx.x;
    const int tid = threadIdx.x;
    if (tid < BB) tok_s[tid] = tokens[tid * TT + t];

    const int tb = tid >> 4;
    const int tg = tid & 15;
    const int b0 = tb * 4;
    const int g0 = tg * 20;
    const bool active = (tg < 15);

    float acc[4][20];
#pragma unroll
    for (int i = 0; i < 4; ++i)
#pragma unroll
        for (int j = 0; j < 20; ++j) acc[i][j] = 0.f;

    __syncthreads();

    for (int h0 = 0; h0 < H; h0 += KC) {
        for (int i = tid; i < BB * 32; i += 256) {
            int b = i >> 5, k = i & 31;
            if (k < KC) x_s[k][b] = emb[tok_s[b] * H + h0 + k];
        }
        for (int i = tid; i < KC * H; i += 256) {
            int k = i / H, g = i - k * H;
            ut_s[k][g] = Ut[(h0 + k) * H + g];
        }
        __syncthreads();
        if (active) {
#pragma unroll 2
            for (int k = 0; k < KC; ++k) {
                float4 xa = *reinterpret_cast<const float4*>(&x_s[k][b0]);
                float4 u0 = *reinterpret_cast<const float4*>(&ut_s[k][g0 + 0]);
                float4 u1 = *reinterpret_cast<const float4*>(&ut_s[k][g0 + 4]);
                float4 u2 = *reinterpret_cast<const float4*>(&ut_s[k][g0 + 8]);
                float4 u3 = *reinterpret_cast<const float4*>(&ut_s[k][g0 + 12]);
                float4 u4 = *reinterpret_cast<const float4*>(&ut_s[k][g0 + 16]);
                const float xr[4] = {xa.x, xa.y, xa.z, xa.w};
                const float ur[20] = {u0.x, u0.y, u0.z, u0.w,
                                      u1.x, u1.y, u1.z, u1.w,
                                      u2.x, u2.y, u2.z, u2.w,
                                      u3.x, u3.y, u3.z, u3.w,
                                      u4.x, u4.y, u4.z, u4.w};
#pragma unroll
                for (int i = 0; i < 4; ++i)
#pragma unroll
                    for (int j = 0; j < 20; ++j)
                        acc[i][j] += xr[i] * ur[j];
            }
        }
        __syncthreads();
    }

    if (active) {
#pragma unroll
        for (int i = 0; i < 4; ++i) {
            float* dst = ux + (t * BB + b0 + i) * H + g0;
#pragma unroll
            for (int jq = 0; jq < 5; ++jq) {
                *reinterpret_cast<float4*>(dst + jq * 4) =
                    make_float4(acc[i][jq * 4 + 0], acc[i][jq * 4 + 1],
                                acc[i][jq * 4 + 2], acc[i][jq * 4 + 3]);
            }
        }
    }
}

// ---------- recurrence: one block per batch, 512 threads (8 waves) ----------
// Geometry: 8 waves -> 2 waves/EU -> VGPR cap 256 (15-wave blocks cap at 128 and
// the allocator bailed to 64 three rounds running). Thread tt<450: c=tt/150,
// g2=tt%150 owns rows {g2, g2+150} over h-chunk [c*100, c*100+100):
// 200 W floats/thread as NAMED SCALARS + ~35 working ~= 235 demand < 256 cap.
#define REP25(X) X(0) X(1) X(2) X(3) X(4) X(5) X(6) X(7) X(8) X(9) \
    X(10) X(11) X(12) X(13) X(14) X(15) X(16) X(17) X(18) X(19) \
    X(20) X(21) X(22) X(23) X(24)

__global__ __attribute__((amdgpu_flat_work_group_size(512, 512), amdgpu_waves_per_eu(2, 2)))
void rnn_k(const float* __restrict__ W,     // W[g][h] read directly
           const float* __restrict__ ux,    // [T][B][H]
           const float* __restrict__ ihs,
           float* __restrict__ hlast) {
    __shared__ __align__(16) float h_s[304];
    __shared__ float p_s[608];               // [0..299]=c1 partials, [304..603]=c2
    const int b = blockIdx.x;
    const int tid = threadIdx.x;
    const int tt = (tid < 450) ? tid : 449;  // waves 7 tail duplicates (449); writes guarded
    const int c = tt / 150;                  // h-chunk 0..2
    const int g2 = tt - c * 150;             // row pair index 0..149

    const float* wr0 = W + (size_t)g2 * H + c * 100;          // row g2
    const float* wr1 = W + (size_t)(g2 + 150) * H + c * 100;  // row g2+150

    // 200 named scalar W values (no tuple alignment constraints for the allocator)
#define WDECL(q) \
    float a##q##0 = wr0[4*q+0], a##q##1 = wr0[4*q+1], a##q##2 = wr0[4*q+2], a##q##3 = wr0[4*q+3]; \
    float b##q##0 = wr1[4*q+0], b##q##1 = wr1[4*q+1], b##q##2 = wr1[4*q+2], b##q##3 = wr1[4*q+3];
    REP25(WDECL)
#undef WDECL

    if (tid < H) h_s[tid] = ihs[b * H + tid];

    const float* uxb = ux + b * H;
    float u0 = 0.f, u1 = 0.f;
    if (tid < 150) {                          // prefetch t=0
        u0 = uxb[g2];
        u1 = uxb[150 + g2];
    }
    __syncthreads();

    const float4* hs4 = reinterpret_cast<const float4*>(h_s);
    const int hoff = c * 25;

#pragma unroll 1
    for (int t = 0; t < TT; ++t) {
        float n0 = 0.f, n1 = 0.f;
        if (tid < 150 && t + 1 < TT) {        // prefetch t+1 (hides global latency)
            const float* nx = uxb + (t + 1) * (BB * H);
            n0 = nx[g2];
            n1 = nx[150 + g2];
        }
        float accA0 = 0.f, accA1 = 0.f, accA2 = 0.f, accA3 = 0.f;
        float accB0 = 0.f, accB1 = 0.f, accB2 = 0.f, accB3 = 0.f;
#define WSTEP(q) { float4 h4 = hs4[hoff + q]; \
        accA0 += a##q##0 * h4.x; accA1 += a##q##1 * h4.y; \
        accA2 += a##q##2 * h4.z; accA3 += a##q##3 * h4.w; \
        accB0 += b##q##0 * h4.x; accB1 += b##q##1 * h4.y; \
        accB2 += b##q##2 * h4.z; accB3 += b##q##3 * h4.w; }
        REP25(WSTEP)
#undef WSTEP
        float accA = (accA0 + accA1) + (accA2 + accA3);
        float accB = (accB0 + accB1) + (accB2 + accB3);
        if (tid < 450 && c == 1) { p_s[g2] = accA; p_s[150 + g2] = accB; }
        if (tid < 450 && c == 2) { p_s[304 + g2] = accA; p_s[454 + g2] = accB; }
        __syncthreads();
        if (tid < 150) {
            float z0 = accA + p_s[g2] + p_s[304 + g2] + u0;
            float z1 = accB + p_s[150 + g2] + p_s[454 + g2] + u1;
            // tanh(z) = 1 - 2/(exp(2z)+1); limits give +/-1 exactly
            float e0 = __expf(2.f * z0);
            float e1 = __expf(2.f * z1);
            h_s[g2]       = 1.f - 2.f * __builtin_amdgcn_rcpf(e0 + 1.f);
            h_s[150 + g2] = 1.f - 2.f * __builtin_amdgcn_rcpf(e1 + 1.f);
        }
        u0 = n0; u1 = n1;
        __syncthreads();
    }
    if (tid < H) hlast[b * H + tid] = h_s[tid];
}

// ---------- logits: out[b][v] = h_last[b] . Wout[v] + bout[v] ----------
// 256 threads / 4 waves; wave handles 16 v-rows via WAVE-UNIFORM base pointer
// (readfirstlane -> s_load path; r3 dropped this and paid ~140us).
__global__ __launch_bounds__(256) void logits_k(const float* __restrict__ hlast,
                                                const float* __restrict__ Wout,
                                                const float* __restrict__ bout,
                                                float* __restrict__ out) {
    __shared__ float hT[152 * 65];
    const int tid = threadIdx.x;
    const int lane = tid & 63;                 // = b
    const int wv = tid >> 6;
    const int v0 = blockIdx.x * 64;
    const int vb0 = __builtin_amdgcn_readfirstlane(v0 + wv * 16);
    const float* wb = Wout + (size_t)vb0 * H;  // wave-uniform base
    const bool full = (vb0 + 16 <= VV);        // uniform

    float acc[16];
#pragma unroll
    for (int r = 0; r < 16; ++r) acc[r] = 0.f;

    for (int p = 0; p < 2; ++p) {
        const int hbase = p ? 148 : 0;
        const int hn = p ? 152 : 148;
        __syncthreads();
        for (int i = tid; i < BB * hn; i += 256) {
            int b = i / hn, h = i - b * hn;
            hT[h * 65 + b] = hlast[b * H + hbase + h];
        }
        __syncthreads();
        if (full) {
            for (int hc = 0; hc < hn; hc += 4) {
                float hv0 = hT[(hc + 0) * 65 + lane];
                float hv1 = hT[(hc + 1) * 65 + lane];
                float hv2 = hT[(hc + 2) * 65 + lane];
                float hv3 = hT[(hc + 3) * 65 + lane];
#pragma unroll
                for (int r = 0; r < 16; ++r) {
                    const float4 w4 = *reinterpret_cast<const float4*>(wb + r * H + hbase + hc);
                    acc[r] += hv0 * w4.x + hv1 * w4.y + hv2 * w4.z + hv3 * w4.w;
                }
            }
        } else {
            for (int hc = 0; hc < hn; hc += 4) {
                float hv0 = hT[(hc + 0) * 65 + lane];
                float hv1 = hT[(hc + 1) * 65 + lane];
                float hv2 = hT[(hc + 2) * 65 + lane];
                float hv3 = hT[(hc + 3) * 65 + lane];
#pragma unroll
                for (int r = 0; r < 16; ++r) {
                    int vr = vb0 + r; if (vr > VV - 1) vr = VV - 1;   // uniform clamp
                    const float4 w4 = *reinterpret_cast<const float4*>(
                        Wout + (size_t)vr * H + hbase + hc);
                    acc[r] += hv0 * w4.x + hv1 * w4.y + hv2 * w4.z + hv3 * w4.w;
                }
            }
        }
    }

    __syncthreads();
#pragma unroll
    for (int r = 0; r < 16; ++r) hT[(wv * 16 + r) * 65 + lane] = acc[r];
    __syncthreads();
#pragma unroll
    for (int k = 0; k < 16; ++k) {
        int i = tid + k * 256;
        int v = i & 63, bb = i >> 6;
        if (v0 + v < VV)
            out[(size_t)bb * VV + v0 + v] = hT[v * 65 + bb] + bout[v0 + v];
    }
}

extern "C" void kernel_launch(void* const* d_in, const int* in_sizes, int n_in,
                              void* d_out, int out_size, void* d_ws, size_t ws_size,
                              hipStream_t stream) {
    const float* ihs    = (const float*)d_in[0];
    const int*   tokens = (const int*)  d_in[1];
    const float* emb    = (const float*)d_in[2];
    const float* W      = (const float*)d_in[3];
    const float* U      = (const float*)d_in[4];
    const float* Wout   = (const float*)d_in[5];
    const float* bout   = (const float*)d_in[6];
    float* out = (float*)d_out;

    char* ws = (char*)d_ws;
    float* Ut    = (float*)(ws + 0);          // 360,000 B
    float* hlast = (float*)(ws + 400000);     // 76,800 B
    float* ux    = (float*)(ws + 1048576);    // 39,321,600 B  [T][B][H]

    const int tp_blocks = (H * H + 255) / 256;
    transpose_k<<<tp_blocks, 256, 0, stream>>>(U, Ut);
    ux_k<<<TT, 256, 0, stream>>>(tokens, emb, Ut, ux);
    rnn_k<<<BB, 512, 0, stream>>>(W, ux, ihs, hlast);
    logits_k<<<(VV + 63) / 64, 256, 0, stream>>>(hlast, Wout, bout, out);
}

// Round 5
// 811.494 us; speedup vs baseline: 1.3258x; 1.0544x over previous
//
#include <hip/hip_runtime.h>
#include <math.h>

#define H 300
#define BB 64
#define TT 512
#define VV 50257
#define KC 30

// ---------- transpose 300x300: out[r][c] = in[c][r] (U only) ----------
__global__ void transpose_k(const float* __restrict__ in, float* __restrict__ out) {
    int idx = blockIdx.x * blockDim.x + threadIdx.x;
    if (idx < H * H) {
        int r = idx / H, c = idx - r * H;
        out[idx] = in[c * H + r];
    }
}

// ---------- ux[t][b][g] = sum_h emb[tok[b][t]][h] * U[g][h] ----------
__global__ __launch_bounds__(256) void ux_k(const int* __restrict__ tokens,
                                            const float* __restrict__ emb,
                                            const float* __restrict__ Ut,   // Ut[h][g] = U[g][h]
                                            float* __restrict__ ux) {
    __shared__ __align__(16) float x_s[KC][BB];
    __shared__ __align__(16) float ut_s[KC][304];
    __shared__ int tok_s[BB];

    const int t = blockIdx.x;
    const int tid = threadIdx.x;
    if (tid < BB) tok_s[tid] = tokens[tid * TT + t];

    const int tb = tid >> 4;
    const int tg = tid & 15;
    const int b0 = tb * 4;
    const int g0 = tg * 20;
    const bool active = (tg < 15);

    float acc[4][20];
#pragma unroll
    for (int i = 0; i < 4; ++i)
#pragma unroll
        for (int j = 0; j < 20; ++j) acc[i][j] = 0.f;

    __syncthreads();

    for (int h0 = 0; h0 < H; h0 += KC) {
        for (int i = tid; i < BB * 32; i += 256) {
            int b = i >> 5, k = i & 31;
            if (k < KC) x_s[k][b] = emb[tok_s[b] * H + h0 + k];
        }
        for (int i = tid; i < KC * H; i += 256) {
            int k = i / H, g = i - k * H;
            ut_s[k][g] = Ut[(h0 + k) * H + g];
        }
        __syncthreads();
        if (active) {
#pragma unroll 2
            for (int k = 0; k < KC; ++k) {
                float4 xa = *reinterpret_cast<const float4*>(&x_s[k][b0]);
                float4 u0 = *reinterpret_cast<const float4*>(&ut_s[k][g0 + 0]);
                float4 u1 = *reinterpret_cast<const float4*>(&ut_s[k][g0 + 4]);
                float4 u2 = *reinterpret_cast<const float4*>(&ut_s[k][g0 + 8]);
                float4 u3 = *reinterpret_cast<const float4*>(&ut_s[k][g0 + 12]);
                float4 u4 = *reinterpret_cast<const float4*>(&ut_s[k][g0 + 16]);
                const float xr[4] = {xa.x, xa.y, xa.z, xa.w};
                const float ur[20] = {u0.x, u0.y, u0.z, u0.w,
                                      u1.x, u1.y, u1.z, u1.w,
                                      u2.x, u2.y, u2.z, u2.w,
                                      u3.x, u3.y, u3.z, u3.w,
                                      u4.x, u4.y, u4.z, u4.w};
#pragma unroll
                for (int i = 0; i < 4; ++i)
#pragma unroll
                    for (int j = 0; j < 20; ++j)
                        acc[i][j] += xr[i] * ur[j];
            }
        }
        __syncthreads();
    }

    if (active) {
#pragma unroll
        for (int i = 0; i < 4; ++i) {
            float* dst = ux + (t * BB + b0 + i) * H + g0;
#pragma unroll
            for (int jq = 0; jq < 5; ++jq) {
                *reinterpret_cast<float4*>(dst + jq * 4) =
                    make_float4(acc[i][jq * 4 + 0], acc[i][jq * 4 + 1],
                                acc[i][jq * 4 + 2], acc[i][jq * 4 + 3]);
            }
        }
    }
}

// ---------- recurrence: one block per batch, 512 threads (8 waves) ----------
// Worker tt<450: c=tt/150, g2=tt%150 owns rows {g2, g2+150} over h-chunk
// [c*100, c*100+100) = 25 quads/row. Register W: row A quads 0..18 (19) +
// row B quads 0..19 (20) = 156 floats. LDS W: remaining 11 quads/worker
// (79.2 KB). KEY: total LDS 82.8 KB > 80 KB forces 1 block/CU -> 2 waves/EU
// is a HW fact the compiler must accept -> VGPR budget 256 (r1-r4: with tiny
// LDS the compiler kept targeting 4+ waves/EU and spilled W to scratch/L2).
#define RNN_REP19(X) X(0) X(1) X(2) X(3) X(4) X(5) X(6) X(7) X(8) X(9) \
    X(10) X(11) X(12) X(13) X(14) X(15) X(16) X(17) X(18)

__global__ __attribute__((amdgpu_flat_work_group_size(512, 512), amdgpu_waves_per_eu(2, 2)))
void rnn_k(const float* __restrict__ W,     // W[g][h] read directly
           const float* __restrict__ ux,    // [T][B][H]
           const float* __restrict__ ihs,
           float* __restrict__ hlast) {
    __shared__ __align__(16) float4 wl4_s[450 * 11];   // 79,200 B
    __shared__ __align__(16) float h_s[304];
    __shared__ float p_s[608];
    const int b = blockIdx.x;
    const int tid = threadIdx.x;
    const int tt = (tid < 450) ? tid : 449;  // tail duplicates; writes guarded
    const int c = tt / 150;                  // h-chunk 0..2
    const int g2 = tt - c * 150;             // row pair index 0..149

    const float4* wrA4 = reinterpret_cast<const float4*>(W + (size_t)g2 * H + c * 100);
    const float4* wrB4 = reinterpret_cast<const float4*>(W + (size_t)(g2 + 150) * H + c * 100);

#define RNN_WA(q) float4 wa##q = wrA4[q];
    RNN_REP19(RNN_WA)
#undef RNN_WA
#define RNN_WB(q) float4 wb##q = wrB4[q];
    RNN_REP19(RNN_WB)
#undef RNN_WB
    float4 wb19 = wrB4[19];

    const int wbase = tt * 11;
#pragma unroll
    for (int i = 0; i < 6; ++i) wl4_s[wbase + i] = wrA4[19 + i];      // A quads 19..24
#pragma unroll
    for (int i = 0; i < 5; ++i) wl4_s[wbase + 6 + i] = wrB4[20 + i];  // B quads 20..24

    if (tid < H) h_s[tid] = ihs[b * H + tid];

    const float* uxb = ux + b * H;
    float u0 = 0.f, u1 = 0.f;
    if (tid < 150) {                          // prefetch t=0
        u0 = uxb[g2];
        u1 = uxb[150 + g2];
    }
    __syncthreads();

    const float4* hs4 = reinterpret_cast<const float4*>(h_s);
    const int hoff = c * 25;

#pragma unroll 1
    for (int t = 0; t < TT; ++t) {
        float n0 = 0.f, n1 = 0.f;
        if (tid < 150 && t + 1 < TT) {        // prefetch t+1
            const float* nx = uxb + (t + 1) * (BB * H);
            n0 = nx[g2];
            n1 = nx[150 + g2];
        }
        float accA0 = 0.f, accA1 = 0.f, accA2 = 0.f, accA3 = 0.f;
        float accB0 = 0.f, accB1 = 0.f, accB2 = 0.f, accB3 = 0.f;
#define RNN_Q(q) { float4 h4 = hs4[hoff + q]; \
        accA0 += wa##q.x * h4.x; accA1 += wa##q.y * h4.y; \
        accA2 += wa##q.z * h4.z; accA3 += wa##q.w * h4.w; \
        accB0 += wb##q.x * h4.x; accB1 += wb##q.y * h4.y; \
        accB2 += wb##q.z * h4.z; accB3 += wb##q.w * h4.w; }
        RNN_REP19(RNN_Q)
#undef RNN_Q
        {   // q = 19: A from LDS, B from register
            float4 h4 = hs4[hoff + 19];
            float4 wA = wl4_s[wbase + 0];
            accA0 += wA.x * h4.x; accA1 += wA.y * h4.y;
            accA2 += wA.z * h4.z; accA3 += wA.w * h4.w;
            accB0 += wb19.x * h4.x; accB1 += wb19.y * h4.y;
            accB2 += wb19.z * h4.z; accB3 += wb19.w * h4.w;
        }
#pragma unroll
        for (int q = 20; q < 25; ++q) {       // both rows from LDS
            float4 h4 = hs4[hoff + q];
            float4 wA = wl4_s[wbase + (q - 19)];
            float4 wB = wl4_s[wbase + 6 + (q - 20)];
            accA0 += wA.x * h4.x; accA1 += wA.y * h4.y;
            accA2 += wA.z * h4.z; accA3 += wA.w * h4.w;
            accB0 += wB.x * h4.x; accB1 += wB.y * h4.y;
            accB2 += wB.z * h4.z; accB3 += wB.w * h4.w;
        }
        float accA = (accA0 + accA1) + (accA2 + accA3);
        float accB = (accB0 + accB1) + (accB2 + accB3);
        if (tid < 450 && c == 1) { p_s[g2] = accA; p_s[150 + g2] = accB; }
        if (tid < 450 && c == 2) { p_s[304 + g2] = accA; p_s[454 + g2] = accB; }
        __syncthreads();
        if (tid < 150) {
            float z0 = accA + p_s[g2] + p_s[304 + g2] + u0;
            float z1 = accB + p_s[150 + g2] + p_s[454 + g2] + u1;
            float e0 = __expf(2.f * z0);
            float e1 = __expf(2.f * z1);
            h_s[g2]       = 1.f - 2.f * __builtin_amdgcn_rcpf(e0 + 1.f);
            h_s[150 + g2] = 1.f - 2.f * __builtin_amdgcn_rcpf(e1 + 1.f);
        }
        u0 = n0; u1 = n1;
        __syncthreads();
    }
    if (tid < H) hlast[b * H + tid] = h_s[tid];
}

// ---------- logits: tiled GEMM  C[64,50257] = h[64,300] . Wout^T ----------
// Block tile [64 b x 128 v], 256 threads, micro-tile 8b x 4v per thread.
// h-chunks of 32 staged in LDS; Wout staged transposed (coalesced global
// reads, every byte read once -> 60 MB total at HBM rate). Replaces the
// "uniform s_load" design that was secretly ~300us (per-lane replays).
__global__ __launch_bounds__(256) void logits_k(const float* __restrict__ hlast,
                                                const float* __restrict__ Wout,
                                                const float* __restrict__ bout,
                                                float* __restrict__ out) {
    __shared__ __align__(16) float Ws[32 * 132];   // Ws[h'][v'], stride 132
    __shared__ __align__(16) float hs[32 * 76];    // hs[h'][b],  stride 76
    const int tid = threadIdx.x;
    const int tv = tid & 31;          // v' = tv*4
    const int tb = tid >> 5;          // b0 = tb*8
    const int v0 = blockIdx.x * 128;

    float acc[8][4];
#pragma unroll
    for (int i = 0; i < 8; ++i)
#pragma unroll
        for (int j = 0; j < 4; ++j) acc[i][j] = 0.f;

    for (int hb = 0; hb < H; hb += 32) {
        __syncthreads();
        {   // stage Wout tile transposed: thread -> (v'=tid>>1, half q=tid&1)
            const int vp = tid >> 1;
            const int hloc = (tid & 1) * 16;
            int vv = v0 + vp; if (vv > VV - 1) vv = VV - 1;
            const float* wrow = Wout + (size_t)vv * H + hb + hloc;
#pragma unroll
            for (int i = 0; i < 4; ++i) {
                const int hg = hb + hloc + i * 4;
                float4 val;
                if (hg + 3 < H) {
                    val = *reinterpret_cast<const float4*>(wrow + i * 4);
                } else {
                    val.x = (hg + 0 < H) ? wrow[i * 4 + 0] : 0.f;
                    val.y = (hg + 1 < H) ? wrow[i * 4 + 1] : 0.f;
                    val.z = (hg + 2 < H) ? wrow[i * 4 + 2] : 0.f;
                    val.w = (hg + 3 < H) ? wrow[i * 4 + 3] : 0.f;
                }
                Ws[(hloc + i * 4 + 0) * 132 + vp] = val.x;
                Ws[(hloc + i * 4 + 1) * 132 + vp] = val.y;
                Ws[(hloc + i * 4 + 2) * 132 + vp] = val.z;
                Ws[(hloc + i * 4 + 3) * 132 + vp] = val.w;
            }
        }
        {   // stage h tile transposed: thread -> (b=tid>>2, 8 h's)
            const int bb = tid >> 2;
            const int hl = (tid & 3) * 8;
            const float* hrow = hlast + bb * H + hb + hl;
#pragma unroll
            for (int i = 0; i < 2; ++i) {
                const int hg = hb + hl + i * 4;
                float4 val;
                if (hg + 3 < H) {
                    val = *reinterpret_cast<const float4*>(hrow + i * 4);
                } else {
                    val.x = (hg + 0 < H) ? hrow[i * 4 + 0] : 0.f;
                    val.y = (hg + 1 < H) ? hrow[i * 4 + 1] : 0.f;
                    val.z = (hg + 2 < H) ? hrow[i * 4 + 2] : 0.f;
                    val.w = (hg + 3 < H) ? hrow[i * 4 + 3] : 0.f;
                }
                hs[(hl + i * 4 + 0) * 76 + bb] = val.x;
                hs[(hl + i * 4 + 1) * 76 + bb] = val.y;
                hs[(hl + i * 4 + 2) * 76 + bb] = val.z;
                hs[(hl + i * 4 + 3) * 76 + bb] = val.w;
            }
        }
        __syncthreads();
        const float4* Ws4 = reinterpret_cast<const float4*>(Ws);  // stride 33
        const float4* hs4 = reinterpret_cast<const float4*>(hs);  // stride 19
#pragma unroll
        for (int h2 = 0; h2 < 32; ++h2) {
            float4 w4  = Ws4[h2 * 33 + tv];
            float4 h4a = hs4[h2 * 19 + tb * 2];
            float4 h4b = hs4[h2 * 19 + tb * 2 + 1];
            const float hv[8] = {h4a.x, h4a.y, h4a.z, h4a.w,
                                 h4b.x, h4b.y, h4b.z, h4b.w};
#pragma unroll
            for (int bi = 0; bi < 8; ++bi) {
                acc[bi][0] += hv[bi] * w4.x;
                acc[bi][1] += hv[bi] * w4.y;
                acc[bi][2] += hv[bi] * w4.z;
                acc[bi][3] += hv[bi] * w4.w;
            }
        }
    }

    const int vg = v0 + tv * 4;
    float4 bq;
    if (vg + 3 < VV) bq = *reinterpret_cast<const float4*>(bout + vg);
    else {
        bq.x = (vg + 0 < VV) ? bout[vg + 0] : 0.f;
        bq.y = (vg + 1 < VV) ? bout[vg + 1] : 0.f;
        bq.z = (vg + 2 < VV) ? bout[vg + 2] : 0.f;
        bq.w = (vg + 3 < VV) ? bout[vg + 3] : 0.f;
    }
#pragma unroll
    for (int bi = 0; bi < 8; ++bi) {
        const int bb = tb * 8 + bi;
        float* op = out + (size_t)bb * VV + vg;   // VV odd -> rows not 16B-aligned: scalar stores
        if (vg + 0 < VV) op[0] = acc[bi][0] + bq.x;
        if (vg + 1 < VV) op[1] = acc[bi][1] + bq.y;
        if (vg + 2 < VV) op[2] = acc[bi][2] + bq.z;
        if (vg + 3 < VV) op[3] = acc[bi][3] + bq.w;
    }
}

extern "C" void kernel_launch(void* const* d_in, const int* in_sizes, int n_in,
                              void* d_out, int out_size, void* d_ws, size_t ws_size,
                              hipStream_t stream) {
    const float* ihs    = (const float*)d_in[0];
    const int*   tokens = (const int*)  d_in[1];
    const float* emb    = (const float*)d_in[2];
    const float* W      = (const float*)d_in[3];
    const float* U      = (const float*)d_in[4];
    const float* Wout   = (const float*)d_in[5];
    const float* bout   = (const float*)d_in[6];
    float* out = (float*)d_out;

    char* ws = (char*)d_ws;
    float* Ut    = (float*)(ws + 0);          // 360,000 B
    float* hlast = (float*)(ws + 400000);     // 76,800 B
    float* ux    = (float*)(ws + 1048576);    // 39,321,600 B  [T][B][H]

    const int tp_blocks = (H * H + 255) / 256;
    transpose_k<<<tp_blocks, 256, 0, stream>>>(U, Ut);
    ux_k<<<TT, 256, 0, stream>>>(tokens, emb, Ut, ux);
    rnn_k<<<BB, 512, 0, stream>>>(W, ux, ihs, hlast);
    logits_k<<<(VV + 127) / 128, 256, 0, stream>>>(hlast, Wout, bout, out);
}